// Round 2
// baseline (222.941 us; speedup 1.0000x reference)
//
#include <hip/hip_runtime.h>
#include <math.h>

// GaussianSpot: out[1,B,F,14,14] = bg[b,f] + sum_k h/(2*pi*w^2) * exp(-((i-sx)^2+(j-sy)^2)/(2w^2))
// Separable Gaussian. R2 structure:
//   phase 1 (registers only): thread = (AOI p, quarter q). Computes ex[k][4] (coef folded)
//            and ey[k][14] with 36 exp2f, then its 49 pixels with constexpr-unrolled
//            indices, ds_write into a packed per-block image buffer.
//   phase 2: pure LDS->global float4 streaming copy (1 ds_read_b128 + 1 dwordx4 / 16B).
// Write-BW bound: 205.5 MB out -> ~33 us floor at 6.3 TB/s.

#define DD 14
#define BB 512
#define FFRAMES 512
#define NF_TAB 1024
#define PAIRS_PER_BLOCK 64
#define BLOCK 256
#define IMG (DD * DD)   // 196 (divisible by 4: float4 never crosses AOI boundary)

__global__ __launch_bounds__(BLOCK) void gauss_spot_kernel(
    const float* __restrict__ height, const float* __restrict__ width,
    const float* __restrict__ xoff, const float* __restrict__ yoff,
    const float* __restrict__ background, const float* __restrict__ target_locs,
    const int* __restrict__ n_idx, const int* __restrict__ f_tab,
    float* __restrict__ out)
{
    __shared__ float img[PAIRS_PER_BLOCK * IMG];   // 50176 B -> 3 blocks/CU

    const int tid = threadIdx.x;
    const int p = tid >> 2;              // AOI within block (0..63)
    const int q = tid & 3;               // quarter: pixels [49q, 49q+49)
    const int pair = blockIdx.x * PAIRS_PER_BLOCK + p;   // b*F + fi
    const int b = pair >> 9;             // F = 512
    const int fi = pair & (FFRAMES - 1);

    const int n = n_idx[b];              // n_idx is [B,1]
    const int ff = f_tab[fi];
    const float lx = target_locs[(n * NF_TAB + ff) * 2 + 0];  // i-axis center base
    const float ly = target_locs[(n * NF_TAB + ff) * 2 + 1];  // j-axis center base
    const float bg = background[pair];

    // i range for this quarter: q=0 -> 0..3, q=1 -> 3..6, q=2 -> 7..10, q=3 -> 10..13
    const int i_lo = (49 * q) / 14;

    float ex[2][4], ey[2][14];
    #pragma unroll
    for (int k = 0; k < 2; ++k) {
        const int idx = k * (BB * FFRAMES) + pair;
        const float w = width[idx];
        const float h = height[idx];
        const float sx = lx + xoff[idx];
        const float sy = ly + yoff[idx];
        const float inv2w2 = 1.0f / (2.0f * w * w);
        const float coef = h * inv2w2 * 0.31830988618379067f;  // h/(2*pi*w^2)
        const float a = inv2w2 * 1.4426950408889634f;          // log2(e)/(2w^2)
        #pragma unroll
        for (int t = 0; t < 4; ++t) {
            float d = (float)(i_lo + t) - sx;
            ex[k][t] = coef * exp2f(-d * d * a);
        }
        #pragma unroll
        for (int j = 0; j < 14; ++j) {
            float d = (float)j - sy;
            ey[k][j] = exp2f(-d * d * a);
        }
    }

    // phase 1.5: compute 49 pixels, indices compile-time via parity branch.
    // pix = 49q + e = 14*i_lo + j0 + e with j0 = 7*(q&1).
    float* dst = img + p * IMG + 49 * q;
    if (q & 1) {
        #pragma unroll
        for (int e = 0; e < 49; ++e) {
            const int il = (7 + e) / 14, j = (7 + e) % 14;
            dst[e] = bg + ex[0][il] * ey[0][j] + ex[1][il] * ey[1][j];
        }
    } else {
        #pragma unroll
        for (int e = 0; e < 49; ++e) {
            const int il = e / 14, j = e % 14;
            dst[e] = bg + ex[0][il] * ey[0][j] + ex[1][il] * ey[1][j];
        }
    }
    __syncthreads();

    // phase 2: pure streaming copy LDS -> global, fully coalesced float4.
    const float4* src4 = (const float4*)img;
    float4* out4 = (float4*)(out + (size_t)blockIdx.x * (PAIRS_PER_BLOCK * IMG));
    const int NV = PAIRS_PER_BLOCK * IMG / 4;   // 3136 = 12*256 + 64
    #pragma unroll
    for (int it = 0; it < 12; ++it) {
        const int v = tid + it * BLOCK;
        out4[v] = src4[v];
    }
    if (tid < NV - 12 * BLOCK) {
        const int v = tid + 12 * BLOCK;
        out4[v] = src4[v];
    }
}

extern "C" void kernel_launch(void* const* d_in, const int* in_sizes, int n_in,
                              void* d_out, int out_size, void* d_ws, size_t ws_size,
                              hipStream_t stream) {
    const float* height      = (const float*)d_in[0];
    const float* width       = (const float*)d_in[1];
    const float* x           = (const float*)d_in[2];
    const float* y           = (const float*)d_in[3];
    const float* background  = (const float*)d_in[4];
    const float* target_locs = (const float*)d_in[5];
    const int*   n_idx       = (const int*)d_in[6];
    const int*   f           = (const int*)d_in[7];
    float* out = (float*)d_out;

    const int total_pairs = BB * FFRAMES;              // 262144
    const int grid = total_pairs / PAIRS_PER_BLOCK;    // 4096
    gauss_spot_kernel<<<grid, BLOCK, 0, stream>>>(
        height, width, x, y, background, target_locs, n_idx, f, out);
}